// Round 3
// baseline (128.103 us; speedup 1.0000x reference)
//
#include <hip/hip_runtime.h>
#include <math.h>

// x: [B, C, T, F] float32.
// out[b,k,f] = max_{j,t} (x[b,j,t,f] + x[b,k,t,f])
//            = max_t ( x[b,k,t,f] + M[b,t,f] ),  M = max_j x[b,j,t,f]  (exact)
// Fused: block owns (b, t-chunk of TC). Phase A: chunk-local M in LDS (one HBM
// read of the chunk). Phase B: re-read same chunk (L2/L3-hot) + combine, write
// per-chunk partials. Tiny combine kernel folds the NT chunks.
#define B_DIM 8
#define C_DIM 160
#define T_DIM 512
#define F_DIM 32
#define F4 8            // float4 per (b,c,t) row
#define C1 159          // output channels k = 0..C-2
#define TC 8            // t per chunk
#define NT (T_DIM / TC) // 64 chunks per b

__device__ __forceinline__ float4 fmax4(float4 a, float4 b) {
    return make_float4(fmaxf(a.x, b.x), fmaxf(a.y, b.y),
                       fmaxf(a.z, b.z), fmaxf(a.w, b.w));
}
__device__ __forceinline__ float4 fadd4(float4 a, float4 b) {
    return make_float4(a.x + b.x, a.y + b.y, a.z + b.z, a.w + b.w);
}
__device__ __forceinline__ float4 shfl_xor4(float4 v, int m) {
    return make_float4(__shfl_xor(v.x, m), __shfl_xor(v.y, m),
                       __shfl_xor(v.z, m), __shfl_xor(v.w, m));
}
#define NEG_INF4 make_float4(-INFINITY, -INFINITY, -INFINITY, -INFINITY)

// Grid: B*NT blocks of 256. partial layout: [b][k][tc][f4] (float4 units).
__global__ __launch_bounds__(256)
void fused_kernel(const float* __restrict__ x, float* __restrict__ partial) {
    const int blk = blockIdx.x;
    const int b = blk >> 6;                 // / NT
    const int tc = blk & (NT - 1);
    const int t_base = tc * TC;
    const int tid = threadIdx.x;
    const int f4 = tid & 7;

    const float4* __restrict__ x4 = (const float4*)x;
    float4* __restrict__ p4 = (float4*)partial;

    __shared__ float4 red[256];
    __shared__ float4 Mlds[TC * F4];        // 64 float4 = 1 KB

    // ---- Phase A: Mlds[tl*8+f4] = max_c x[b,c,t_base+tl,f4] ----
    {
        const int tl = (tid >> 3) & 7;
        const int cs = tid >> 6;            // 0..3 channel slice
        const int base = (b * C_DIM * T_DIM + (t_base + tl)) * F4 + f4;
        float4 acc = NEG_INF4;
        #pragma unroll 8
        for (int i = 0; i < 40; ++i) {      // each wave-load: 1 KB contiguous
            const int c = i * 4 + cs;
            acc = fmax4(acc, x4[base + c * (T_DIM * F4)]);
        }
        red[tid] = acc;
        __syncthreads();
        if (tid < 128) red[tid] = fmax4(red[tid], red[tid + 128]);
        __syncthreads();
        if (tid < 64) Mlds[tid] = fmax4(red[tid], red[tid + 64]);
        __syncthreads();
    }

    // ---- Phase B: partial[b,k,tc,f4] = max_{tl} (x[b,k,t,f4] + M[tl,f4]) ----
    {
        const int kg = tid >> 3;            // 0..31
        float4 m[TC];
        #pragma unroll
        for (int tl = 0; tl < TC; ++tl) m[tl] = Mlds[tl * 8 + f4];

        #pragma unroll
        for (int ki = 0; ki < 5; ++ki) {
            const int k = kg + 32 * ki;     // covers 0..158 (+159 skipped)
            if (k < C1) {
                const float4* __restrict__ xk =
                    x4 + ((b * C_DIM + k) * T_DIM + t_base) * F4 + f4;
                float4 acc = NEG_INF4;
                #pragma unroll
                for (int tl = 0; tl < TC; ++tl)
                    acc = fmax4(acc, fadd4(xk[tl * F4], m[tl]));
                p4[((b * C1 + k) * NT + tc) * F4 + f4] = acc;
            }
        }
    }
}

// Grid: B*C1 waves. out[b,k,f] = max_tc partial[b,k,tc,f].
__global__ __launch_bounds__(64)
void combine_kernel(const float* __restrict__ partial, float* __restrict__ out) {
    const int bk = blockIdx.x;              // b*C1 + k
    const int lane = threadIdx.x;
    const float4* __restrict__ p = (const float4*)partial + bk * (NT * F4);

    float4 acc = NEG_INF4;
    #pragma unroll
    for (int j = 0; j < (NT * F4) / 64; ++j)    // 8 iters, fully coalesced
        acc = fmax4(acc, p[j * 64 + lane]);

    acc = fmax4(acc, shfl_xor4(acc, 8));
    acc = fmax4(acc, shfl_xor4(acc, 16));
    acc = fmax4(acc, shfl_xor4(acc, 32));
    if (lane < 8)
        ((float4*)out)[bk * F4 + lane] = acc;   // flat bk*F + lane*4
}

extern "C" void kernel_launch(void* const* d_in, const int* in_sizes, int n_in,
                              void* d_out, int out_size, void* d_ws, size_t ws_size,
                              hipStream_t stream) {
    const float* x = (const float*)d_in[0];
    float* out = (float*)d_out;
    float* partial = (float*)d_ws;  // B*C1*NT*F = 10.4 MB scratch

    fused_kernel<<<B_DIM * NT, 256, 0, stream>>>(x, partial);     // 512 blocks
    combine_kernel<<<B_DIM * C1, 64, 0, stream>>>(partial, out);  // 1272 waves
}

// Round 4
// 120.549 us; speedup vs baseline: 1.0627x; 1.0627x over previous
//
#include <hip/hip_runtime.h>
#include <math.h>

// x: [B, C, T, F] float32.
// out[b,k,f] = max_{j,t} (x[b,j,t,f] + x[b,k,t,f])
//            = max_t ( x[b,k,t,f] + M[b,t,f] ),  M = max_j x[b,j,t,f]  (exact:
//              fl(a+b) is monotone in b, so rounded-add commutes with max)
//
// Single HBM pass: block owns (b, 8-t chunk); loops 4 sub-chunks of 2 t.
// Each sub-chunk (160c x 2t x 32f = 40 KB) is staged to LDS while the
// channel-max M_sub is computed in-register (shfl reduce). Phase B then reads
// x[k] from LDS (not L2/L3) and accumulates into registers. Partials
// [B,C1,NT,F] are folded by a tiny combine kernel.
#define B_DIM 8
#define C_DIM 160
#define T_DIM 512
#define F_DIM 32
#define F4 8              // float4 per (b,c,t) row
#define C1 159            // output channels k = 0..C-2
#define TCH 8             // t per chunk (per block)
#define NT (T_DIM / TCH)  // 64 chunks per b
#define NSUB 4            // sub-chunks per chunk (2 t each)
#define KPAD 17           // padded k-row stride in float4 (16 data + 1 pad)

__device__ __forceinline__ float4 fmax4(float4 a, float4 b) {
    return make_float4(fmaxf(a.x, b.x), fmaxf(a.y, b.y),
                       fmaxf(a.z, b.z), fmaxf(a.w, b.w));
}
__device__ __forceinline__ float4 fadd4(float4 a, float4 b) {
    return make_float4(a.x + b.x, a.y + b.y, a.z + b.z, a.w + b.w);
}
__device__ __forceinline__ float4 shfl_xor4(float4 v, int m) {
    return make_float4(__shfl_xor(v.x, m), __shfl_xor(v.y, m),
                       __shfl_xor(v.z, m), __shfl_xor(v.w, m));
}
#define NEG_INF4 make_float4(-INFINITY, -INFINITY, -INFINITY, -INFINITY)

// Grid: B*NT blocks of 256. partial layout: [b][k][tc][f4] (float4 units).
__global__ __launch_bounds__(256)
void fused_kernel(const float* __restrict__ x, float* __restrict__ partial) {
    const int blk = blockIdx.x;
    const int b = blk >> 6;                 // / NT
    const int tc = blk & (NT - 1);
    const int t_base = tc * TCH;
    const int tid = threadIdx.x;
    const int f4 = tid & 7;
    const int eid = tid & 15;               // (tl<<3)|f4 within a 2-t sub-chunk
    const int cg = tid >> 4;                // 0..15 channel group
    const int wave = tid >> 6;              // 0..3

    const float4* __restrict__ x4 = (const float4*)x;
    float4* __restrict__ p4 = (float4*)partial;

    __shared__ float4 Xlds[C_DIM * KPAD];   // 160 x 17 float4 = 42.5 KB
    __shared__ float4 redw[4 * 16];         // per-wave channel-max partials

    const int kg = tid >> 3;                // 0..31 (Phase B)
    float4 accK[5];
    #pragma unroll
    for (int ki = 0; ki < 5; ++ki) accK[ki] = NEG_INF4;

    for (int s = 0; s < NSUB; ++s) {
        const int t0 = t_base + 2 * s;

        // ---- Phase A: stage sub-chunk to LDS + in-register channel max ----
        float4 macc = NEG_INF4;
        #pragma unroll
        for (int i = 0; i < 10; ++i) {
            const int c = cg + 16 * i;
            // (t0*8 + eid) == (t0 + tl)*8 + f4 : 256 B contiguous per c
            const float4 v = x4[((b * C_DIM + c) * T_DIM + t0) * F4 + eid];
            Xlds[c * KPAD + eid] = v;
            macc = fmax4(macc, v);
        }
        // in-wave reduce over the 4 cg groups per wave (bits 4,5 of lane)
        macc = fmax4(macc, shfl_xor4(macc, 16));
        macc = fmax4(macc, shfl_xor4(macc, 32));
        if ((tid & 63) < 16) redw[wave * 16 + eid] = macc;
        __syncthreads();

        // every thread folds the 4 per-wave partials for its two eids
        float4 m0 = fmax4(fmax4(redw[f4],      redw[16 + f4]),
                          fmax4(redw[32 + f4], redw[48 + f4]));
        float4 m1 = fmax4(fmax4(redw[8 + f4],      redw[16 + 8 + f4]),
                          fmax4(redw[32 + 8 + f4], redw[48 + 8 + f4]));

        // ---- Phase B: accK[ki] = max(accK, x[k, t0+tl, f4] + M[tl]) ----
        #pragma unroll
        for (int ki = 0; ki < 5; ++ki) {
            const int k = kg + 32 * ki;
            if (k < C1) {
                accK[ki] = fmax4(accK[ki],
                                 fadd4(Xlds[k * KPAD + f4], m0));
                accK[ki] = fmax4(accK[ki],
                                 fadd4(Xlds[k * KPAD + 8 + f4], m1));
            }
        }
        __syncthreads();   // before next sub-chunk overwrites Xlds
    }

    #pragma unroll
    for (int ki = 0; ki < 5; ++ki) {
        const int k = kg + 32 * ki;
        if (k < C1)
            p4[((b * C1 + k) * NT + tc) * F4 + f4] = accK[ki];
    }
}

// Grid: B*C1 waves. out[b,k,f] = max_tc partial[b,k,tc,f].
__global__ __launch_bounds__(64)
void combine_kernel(const float* __restrict__ partial, float* __restrict__ out) {
    const int bk = blockIdx.x;              // b*C1 + k
    const int lane = threadIdx.x;
    const float4* __restrict__ p = (const float4*)partial + bk * (NT * F4);

    float4 acc = NEG_INF4;
    #pragma unroll
    for (int j = 0; j < (NT * F4) / 64; ++j)    // 8 iters, fully coalesced
        acc = fmax4(acc, p[j * 64 + lane]);

    acc = fmax4(acc, shfl_xor4(acc, 8));
    acc = fmax4(acc, shfl_xor4(acc, 16));
    acc = fmax4(acc, shfl_xor4(acc, 32));
    if (lane < 8)
        ((float4*)out)[bk * F4 + lane] = acc;   // flat bk*F + lane*4
}

extern "C" void kernel_launch(void* const* d_in, const int* in_sizes, int n_in,
                              void* d_out, int out_size, void* d_ws, size_t ws_size,
                              hipStream_t stream) {
    const float* x = (const float*)d_in[0];
    float* out = (float*)d_out;
    float* partial = (float*)d_ws;  // B*C1*NT*F floats = 10.4 MB scratch

    fused_kernel<<<B_DIM * NT, 256, 0, stream>>>(x, partial);     // 512 blocks
    combine_kernel<<<B_DIM * C1, 64, 0, stream>>>(partial, out);  // 1272 waves
}